// Round 11
// baseline (1071.368 us; speedup 1.0000x reference)
//
#include <hip/hip_runtime.h>
#include <hip/hip_bf16.h>
#include <math.h>
#include <stdint.h>

#define EPS_BN 1e-5f

constexpr int Nx = 8192;
constexpr int NP = 1024;
constexpr int NWORK = 248;   // worker blocks (grid 256 = 8 fps + 248 workers)
constexpr int NEMB  = 128;   // worker blocks 8..135 also embed a 512-pt slice
#define POISON_I ((int)0xAAAAAAAA)

typedef __attribute__((ext_vector_type(8))) __bf16 bf16x8;
typedef __attribute__((ext_vector_type(4))) float  f32x4;
typedef __attribute__((ext_vector_type(2))) float  f32x2;
typedef unsigned int uint32;
typedef unsigned long long u64;

// ---- DPP wave64 reduction helpers ----
template<int CTRL, int RMASK>
__device__ __forceinline__ u64 dpp_max_u64(u64 k) {
    uint32 klo = (uint32)k, khi = (uint32)(k >> 32);
    uint32 plo = (uint32)__builtin_amdgcn_update_dpp((int)klo, (int)klo, CTRL, RMASK, 0xf, false);
    uint32 phi = (uint32)__builtin_amdgcn_update_dpp((int)khi, (int)khi, CTRL, RMASK, 0xf, false);
    u64 p = ((u64)phi << 32) | plo;
    return (p > k) ? p : k;
}
template<int CTRL, int RMASK>
__device__ __forceinline__ float dpp_max_f32(float v) {
    int t = __builtin_amdgcn_update_dpp(__float_as_int(v), __float_as_int(v), CTRL, RMASK, 0xf, false);
    return fmaxf(v, __int_as_float(t));
}
__device__ __forceinline__ float wave_max_f32(float v) {
    v = dpp_max_f32<0x111, 0xf>(v);   // row_shr:1
    v = dpp_max_f32<0x112, 0xf>(v);   // row_shr:2
    v = dpp_max_f32<0x114, 0xf>(v);   // row_shr:4
    v = dpp_max_f32<0x118, 0xf>(v);   // row_shr:8
    v = dpp_max_f32<0x142, 0xa>(v);   // row_bcast:15 -> rows 1,3
    v = dpp_max_f32<0x143, 0xc>(v);   // row_bcast:31 -> rows 2,3
    return __int_as_float(__builtin_amdgcn_readlane(__float_as_int(v), 63));
}
template<int CTRL, int RMASK>
__device__ __forceinline__ int dpp_sum_i32(int c) {
    int t = __builtin_amdgcn_update_dpp(0, c, CTRL, RMASK, 0xf, true);  // OOB -> 0
    return c + t;
}
__device__ __forceinline__ int wave_sum_i32(int c) {
    c = dpp_sum_i32<0x111, 0xf>(c);
    c = dpp_sum_i32<0x112, 0xf>(c);
    c = dpp_sum_i32<0x114, 0xf>(c);
    c = dpp_sum_i32<0x118, 0xf>(c);
    c = dpp_sum_i32<0x142, 0xa>(c);
    c = dpp_sum_i32<0x143, 0xc>(c);
    return __builtin_amdgcn_readlane(c, 63);
}
template<int CTRL, int RMASK>
__device__ __forceinline__ int dpp_min_i32(int v) {
    int t = __builtin_amdgcn_update_dpp(v, v, CTRL, RMASK, 0xf, false);
    return min(v, t);
}
__device__ __forceinline__ int wave_min_i32(int v) {
    v = dpp_min_i32<0x111, 0xf>(v);
    v = dpp_min_i32<0x112, 0xf>(v);
    v = dpp_min_i32<0x114, 0xf>(v);
    v = dpp_min_i32<0x118, 0xf>(v);
    v = dpp_min_i32<0x142, 0xa>(v);
    v = dpp_min_i32<0x143, 0xc>(v);
    return __builtin_amdgcn_readlane(v, 63);
}

// =================== THE single kernel: fps | embed+worker roles ===================
__global__ __launch_bounds__(512, 1) void mega_kernel(
    const float* __restrict__ x,
    const float* __restrict__ w1, const float* __restrict__ w2,
    const float* g1, const float* b1, const float* m1, const float* v1,
    const float* g2, const float* b2, const float* m2, const float* v2,
    const float* __restrict__ lw1, const float* __restrict__ lw2,
    const float* lg1, const float* lb1, const float* lm1, const float* lv1,
    const float* lg2, const float* lb2, const float* lm2, const float* lv2,
    float* __restrict__ f, float4* __restrict__ pts4, int* fpsI, int* done,
    float* __restrict__ out0, float* __restrict__ out1,
    float* __restrict__ out2, float* __restrict__ out3)
{
    __shared__ __attribute__((aligned(16))) char smemRaw[135296];
    int tid = threadIdx.x;

    if (blockIdx.x < 8) {
        // ============ FPS role: barrier-FREE loop, stamped-partial dataflow sync =======
#pragma clang fp contract(off)
        float4* xyzL    = (float4*)smemRaw;                 // 128 KB
        u64*    redK    = (u64*)(smemRaw + 131072);         // [2][8] stamped partials
        int*    farHist = (int*)(smemRaw + 131200);         // 1024 ints
        int b = blockIdx.x;
        int wid = tid >> 6, lane = tid & 63;
        const float* xb = x + (size_t)b * Nx * 3;
        f32x2 px[8], py[8], pz[8], dist[8];    // 16 pts/thread: pair i = pts (16t+2i, 16t+2i+1)
        {
            const float4* xv = (const float4*)(xb + tid * 48);
            float F[48];
#pragma unroll
            for (int q = 0; q < 12; q++) {
                float4 v = xv[q];
                F[q*4+0]=v.x; F[q*4+1]=v.y; F[q*4+2]=v.z; F[q*4+3]=v.w;
            }
#pragma unroll
            for (int i = 0; i < 8; i++) {
                px[i] = (f32x2){F[(2*i)*3+0], F[(2*i+1)*3+0]};
                py[i] = (f32x2){F[(2*i)*3+1], F[(2*i+1)*3+1]};
                pz[i] = (f32x2){F[(2*i)*3+2], F[(2*i+1)*3+2]};
                dist[i] = (f32x2){1e10f, 1e10f};
            }
#pragma unroll
            for (int j = 0; j < 16; j++) {
                int jj = (j + (tid & 15)) & 15;
                xyzL[tid*16 + jj] = make_float4(F[jj*3], F[jj*3+1], F[jj*3+2], 0.f);
            }
        }
        __syncthreads();   // xyzL ready (one-time)
        int far = 0;
        for (int st = 0; st < NP; st++) {
            float4 c = xyzL[far];
            if (tid == 0) farHist[st] = far;        // wave-0 local (lanes 0-15 consume)
            f32x2 cx = {c.x, c.x}, cy = {c.y, c.y}, cz = {c.z, c.z};
            f32x2 bv2 = {-1.0f, -1.0f};
#pragma unroll
            for (int i = 0; i < 8; i++) {
                f32x2 dx = px[i] - cx, dy = py[i] - cy, dz = pz[i] - cz;
                f32x2 sq = (dx*dx + dy*dy) + dz*dz;    // per-lane IEEE, exact np order
                f32x2 dm = __builtin_elementwise_min(dist[i], sq);
                dist[i] = dm;
                bv2 = __builtin_elementwise_max(bv2, dm);
            }
            float bv = fmaxf(bv2.x, bv2.y);
            // per-lane argmax vs OWN bv (overlaps the DPP chain)
            int bi = tid*16;
#pragma unroll
            for (int i = 7; i >= 0; i--) {          // high->low so lowest idx wins
                if (dist[i].y == bv) bi = tid*16 + 2*i + 1;
                if (dist[i].x == bv) bi = tid*16 + 2*i;
            }
            // wave winner: f32 value reduce, ballot picks lowest matching lane
            float wv = wave_max_f32(bv);
            u64 mask = __ballot(bv == wv);
            int first = (int)__builtin_ctzll(mask);
            int wbi = __builtin_amdgcn_readlane(bi, first);
            // stamped partial: stamp bits identical across same-step keys -> ordering intact
            uint32 stamp = (uint32)(st + 1);        // 1..1024, fits 11 bits
            if (lane == 0) {
                u64 k = ((u64)__float_as_uint(wv) << 32) | (stamp << 13) | ((uint32)(~wbi) & 0x1FFFu);
                __hip_atomic_store(&redK[(st & 1)*8 + wid], k,
                                   __ATOMIC_RELAXED, __HIP_MEMORY_SCOPE_WORKGROUP);
            }
            // dataflow sync: spin until all 8 partials carry this step's stamp
            u64 k8;
            {
                volatile u64* src = &redK[(st & 1)*8 + (lane & 7)];
                for (;;) {
                    k8 = __hip_atomic_load((u64*)src, __ATOMIC_RELAXED, __HIP_MEMORY_SCOPE_WORKGROUP);
                    bool ok = (((uint32)k8 >> 13) & 0x7FFu) == stamp;
                    if (__ballot(ok) == ~0ull) break;
                }
            }
            k8 = dpp_max_u64<0x111, 0xf>(k8);
            k8 = dpp_max_u64<0x112, 0xf>(k8);
            k8 = dpp_max_u64<0x114, 0xf>(k8);   // lane 7 = max over lanes 0..7
            far = (int)((~(uint32)__builtin_amdgcn_readlane((int)(uint32)k8, 7)) & 0x1FFFu);
            // batched publish (wave 0 only; farHist written by lane 0 of same wave)
            if ((st & 15) == 15 && tid < 16) {
                int idx = st - 15 + tid;
                __hip_atomic_store(&fpsI[b*NP + idx], farHist[idx],
                                   __ATOMIC_RELAXED, __HIP_MEMORY_SCOPE_AGENT);
            }
        }
        // bulk-write centroid coords (not consumed by workers)
        __syncthreads();
        for (int i = tid; i < NP; i += 512) {
            float4 c = xyzL[farHist[i]];
            int o = (b*NP + i) * 3;
            out0[o]=c.x; out0[o+1]=c.y; out0[o+2]=c.z;
            out2[o]=c.x; out2[o+1]=c.y; out2[o+2]=c.z;
        }
        return;
    }

    // ================= Worker role ====================================================
    int wb = (int)blockIdx.x - 8;

    if (wb < NEMB) {
        // ---- embed a 512-point slice: f + pts4 (LDS overlay, released by sync below) --
        float*  W1L = (float*)smemRaw;                    // 192 f  @0
        float4* W2L = (float4*)(smemRaw + 1024);          // 1024 float4
        float*  s1L = (float*)(smemRaw + 17408);
        float*  m1L = (float*)(smemRaw + 17664);
        float*  b1L = (float*)(smemRaw + 17920);
        float*  s2L = (float*)(smemRaw + 18176);
        float*  m2L = (float*)(smemRaw + 18432);
        float*  b2L = (float*)(smemRaw + 18688);
        if (tid < 192) W1L[tid] = w1[tid];
        for (int i = tid; i < 1024; i += 512) W2L[i] = ((const float4*)w2)[i];
        if (tid < 64) {
            s1L[tid] = g1[tid] * (1.0f / sqrtf(v1[tid] + EPS_BN));
            m1L[tid] = m1[tid];  b1L[tid] = b1[tid];
            s2L[tid] = g2[tid] * (1.0f / sqrtf(v2[tid] + EPS_BN));
            m2L[tid] = m2[tid];  b2L[tid] = b2[tid];
        }
        __syncthreads();
        int n = wb * 512 + tid;                 // 0..65535
        const float* xp = x + (size_t)n * 3;
        float x0 = xp[0], x1 = xp[1], x2 = xp[2];
        {
#pragma clang fp contract(off)
            float nv = (x0 * x0 + x1 * x1) + x2 * x2;   // exact np sum order
            pts4[n] = make_float4(x0, x1, x2, nv);
        }
        float t[64];
#pragma unroll
        for (int e = 0; e < 64; e++) {
            float v = fmaf(x2, W1L[e*3+2], fmaf(x1, W1L[e*3+1], x0 * W1L[e*3]));
            v = (v - m1L[e]) * s1L[e] + b1L[e];
            t[e] = fmaxf(v, 0.0f);
        }
        float acc[64];
#pragma unroll
        for (int o = 0; o < 64; o++) acc[o] = 0.0f;
#pragma unroll
        for (int e4 = 0; e4 < 16; e4++) {
            float a0 = t[e4*4], a1 = t[e4*4+1], a2 = t[e4*4+2], a3 = t[e4*4+3];
#pragma unroll
            for (int o = 0; o < 64; o++) {
                float4 w = W2L[o*16 + e4];
                acc[o] = fmaf(a3, w.w, fmaf(a2, w.z, fmaf(a1, w.y, fmaf(a0, w.x, acc[o]))));
            }
        }
        float4* fo = (float4*)(f + (size_t)n * 64);
#pragma unroll
        for (int q = 0; q < 16; q++) {
            float r0 = fmaxf((acc[q*4+0] - m2L[q*4+0]) * s2L[q*4+0] + b2L[q*4+0], 0.f);
            float r1 = fmaxf((acc[q*4+1] - m2L[q*4+1]) * s2L[q*4+1] + b2L[q*4+1], 0.f);
            float r2 = fmaxf((acc[q*4+2] - m2L[q*4+2]) * s2L[q*4+2] + b2L[q*4+2], 0.f);
            float r3 = fmaxf((acc[q*4+3] - m2L[q*4+3]) * s2L[q*4+3] + b2L[q*4+3], 0.f);
            fo[q] = make_float4(r0, r1, r2, r3);
        }
        __syncthreads();      // LDS free for query phase
        if (tid == 0)
            __hip_atomic_fetch_add(done, 1, __ATOMIC_RELEASE, __HIP_MEMORY_SCOPE_AGENT);
    }

    // ---- query-phase LDS overlay ----
    __bf16* featL = (__bf16*)smemRaw;                 // 8704 B
    __bf16* h1L   = (__bf16*)(smemRaw + 8704);        // 8704 B
    float*  cf    = (float*) (smemRaw + 17408);       // 256 B
    int*    rowL  = (int*)   (smemRaw + 17664);       // 128 B
    int*    redC  = (int*)   (smemRaw + 17792);       // [2][8]
    int*    redM  = (int*)   (smemRaw + 17856);       // [2][8]
    int*    misc  = (int*)   (smemRaw + 17920);       // [0]=cnt [1]=idx

    int wv = tid >> 6, lane = tid & 63;
    int l15 = lane & 15, quad = lane >> 4;
    int nbase = wv * 16;
    const f32x4 vzero = {0.f, 0.f, 0.f, 0.f};

    // per-wave weight fragments / bn params, straight from f32 inputs (no prep kernel)
    bf16x8 bf1[4], bf2[4];
#pragma unroll
    for (int kt = 0; kt < 4; kt++) {
        const float* p1 = lw1 + (size_t)(nbase + l15) * 128 + kt*32 + quad*8;
        const float* p2 = lw2 + (size_t)(nbase + l15) * 128 + kt*32 + quad*8;
        bf16x8 a1, a2;
#pragma unroll
        for (int j = 0; j < 8; j++) { a1[j] = (__bf16)p1[j]; a2[j] = (__bf16)p2[j]; }
        bf1[kt] = a1; bf2[kt] = a2;
    }
    int oc = nbase + l15;
    float sc1 = lg1[oc] * (1.0f / sqrtf(lv1[oc] + EPS_BN));
    float mm1 = lm1[oc], bb1 = lb1[oc];
    float sc2 = lg2[oc] * (1.0f / sqrtf(lv2[oc] + EPS_BN));
    float mm2 = lm2[oc], bb2 = lb2[oc];

    // wait for embed completion (cross-XCD: acquire fence before reading f/pts4)
    if (tid == 0) {
        while (__hip_atomic_load(done, __ATOMIC_RELAXED, __HIP_MEMORY_SCOPE_AGENT) != POISON_I + NEMB)
            __builtin_amdgcn_s_sleep(8);
    }
    __syncthreads();
    __threadfence();

    for (int t = wb; t < 8192; t += NWORK) {
        int b = t & 7, s = t >> 3;          // s-major: workers trail fps monotonically
        int q = (b << 10) | s;
        if (tid == 0) {
            int v;
            while ((v = __hip_atomic_load(&fpsI[q], __ATOMIC_RELAXED, __HIP_MEMORY_SCOPE_AGENT)) < 0)
                __builtin_amdgcn_s_sleep(2);
            misc[1] = v;
            misc[0] = 0;
        }
        __syncthreads();
        int cIdx = misc[1];
        if (tid < 16) {      // center features -> cf (consumed after many barriers)
            float4 v = *(const float4*)(f + ((size_t)b * Nx + cIdx) * 64 + tid * 4);
            cf[tid*4]=v.x; cf[tid*4+1]=v.y; cf[tid*4+2]=v.z; cf[tid*4+3]=v.w;
        }
        // ---- KNN radix-select (512 thr, 16 keys each) ----
        uint32 key[16];
        {
#pragma clang fp contract(off)
            const float4* P = pts4 + (size_t)b * Nx;
            float4 qp = P[cIdx];
#pragma unroll
            for (int i = 0; i < 16; i++) {
                int n = tid + (i << 9);
                float4 p = P[n];
                float dot = (qp.x * p.x + qp.y * p.y) + qp.z * p.z;   // exact ref order
                float d = (qp.w + p.w) - 2.0f * dot;
                uint32 u = __float_as_uint(d);
                key[i] = (u & 0x80000000u) ? ~u : (u | 0x80000000u);
            }
        }
        uint32 prefix = 0; int krem = 32;
        for (int bit = 31; bit >= 0; bit--) {
            uint32 sv = prefix >> bit;
            int cnt = 0;
#pragma unroll
            for (int i = 0; i < 16; i++)
                cnt += ((key[i] >> bit) == sv) ? 1 : 0;
            cnt = wave_sum_i32(cnt);
            if (lane == 0) redC[(bit & 1)*8 + wv] = cnt;
            __syncthreads();
            int total = 0;
#pragma unroll
            for (int j = 0; j < 8; j++) total += redC[(bit & 1)*8 + j];
            if (total < krem) { prefix |= (1u << bit); krem -= total; }
        }
#pragma unroll
        for (int i = 0; i < 16; i++) {
            if (key[i] < prefix) {
                int pos = atomicAdd(&misc[0], 1);
                rowL[pos] = tid + (i << 9);
            }
        }
        __syncthreads();
        int last = -1;
        for (int tt = 0; tt < krem; tt++) {    // krem is block-uniform
            int local = 0x7fffffff;
#pragma unroll
            for (int i = 0; i < 16; i++) {
                int n = tid + (i << 9);
                if (key[i] == prefix && n > last && n < local) local = n;
            }
            local = wave_min_i32(local);
            if (lane == 0) redM[(tt & 1)*8 + wv] = local;
            __syncthreads();
            int g = 0x7fffffff;
#pragma unroll
            for (int j = 0; j < 8; j++) g = min(g, redM[(tt & 1)*8 + j]);
            if (tid == 0) rowL[32 - krem + tt] = g;
            last = g;
        }
        __syncthreads();                        // rowL final
        // ---- build feat = [f_nb - f_c | f_c] in bf16 ----
        {
            int k = tid >> 4, j0 = (tid & 15) * 4;
            int nbr = rowL[k];
            float4 v = *(const float4*)(f + ((size_t)b * Nx + nbr) * 64 + j0);
            float c0 = cf[j0], c1 = cf[j0+1], c2 = cf[j0+2], c3 = cf[j0+3];
            __bf16* dl = featL + k * 136 + j0;
            dl[0]=(__bf16)(v.x-c0); dl[1]=(__bf16)(v.y-c1); dl[2]=(__bf16)(v.z-c2); dl[3]=(__bf16)(v.w-c3);
            __bf16* dr = dl + 64;
            dr[0]=(__bf16)c0; dr[1]=(__bf16)c1; dr[2]=(__bf16)c2; dr[3]=(__bf16)c3;
        }
        __syncthreads();
        // ---- layer 1: (32x128)@(128x16 per wave) ----
        f32x4 acc[2];
        acc[0] = vzero; acc[1] = vzero;
#pragma unroll
        for (int mt = 0; mt < 2; mt++)
#pragma unroll
            for (int kt = 0; kt < 4; kt++) {
                bf16x8 a = *(const bf16x8*)(featL + (mt*16 + l15) * 136 + kt*32 + quad*8);
                acc[mt] = __builtin_amdgcn_mfma_f32_16x16x32_bf16(a, bf1[kt], acc[mt], 0, 0, 0);
            }
#pragma unroll
        for (int mt = 0; mt < 2; mt++)
#pragma unroll
            for (int rj = 0; rj < 4; rj++) {
                float h = fmaxf((acc[mt][rj] - mm1) * sc1 + bb1, 0.0f);
                h1L[(mt*16 + quad*4 + rj) * 136 + oc] = (__bf16)h;
            }
        __syncthreads();
        // ---- layer 2 + k-max ----
        acc[0] = vzero; acc[1] = vzero;
#pragma unroll
        for (int mt = 0; mt < 2; mt++)
#pragma unroll
            for (int kt = 0; kt < 4; kt++) {
                bf16x8 a = *(const bf16x8*)(h1L + (mt*16 + l15) * 136 + kt*32 + quad*8);
                acc[mt] = __builtin_amdgcn_mfma_f32_16x16x32_bf16(a, bf2[kt], acc[mt], 0, 0, 0);
            }
        float vmx = 0.0f;                       // relu => >= 0
#pragma unroll
        for (int mt = 0; mt < 2; mt++)
#pragma unroll
            for (int rj = 0; rj < 4; rj++) {
                float h = fmaxf((acc[mt][rj] - mm2) * sc2 + bb2, 0.0f);
                vmx = fmaxf(vmx, h);
            }
        vmx = fmaxf(vmx, __shfl_xor(vmx, 16));
        vmx = fmaxf(vmx, __shfl_xor(vmx, 32));
        if (quad == 0) {
            size_t off = (size_t)b * (128*1024) + (size_t)oc * 1024 + s;
            out1[off] = vmx;
            out3[off] = vmx;
        }
        __syncthreads();                        // LDS reuse next query
    }
}

extern "C" void kernel_launch(void* const* d_in, const int* in_sizes, int n_in,
                              void* d_out, int out_size, void* d_ws, size_t ws_size,
                              hipStream_t stream)
{
    const float* x    = (const float*)d_in[0];
    const float* c1w  = (const float*)d_in[1];
    const float* c2w  = (const float*)d_in[2];
    const float* l1w  = (const float*)d_in[3];
    const float* l2w  = (const float*)d_in[4];
    const float* bn1g = (const float*)d_in[5];
    const float* bn1b = (const float*)d_in[6];
    const float* bn1m = (const float*)d_in[7];
    const float* bn1v = (const float*)d_in[8];
    const float* bn2g = (const float*)d_in[9];
    const float* bn2b = (const float*)d_in[10];
    const float* bn2m = (const float*)d_in[11];
    const float* bn2v = (const float*)d_in[12];
    const float* lb1g = (const float*)d_in[13];
    const float* lb1b = (const float*)d_in[14];
    const float* lb1m = (const float*)d_in[15];
    const float* lb1v = (const float*)d_in[16];
    const float* lb2g = (const float*)d_in[17];
    const float* lb2b = (const float*)d_in[18];
    const float* lb2m = (const float*)d_in[19];
    const float* lb2v = (const float*)d_in[20];

    float* out = (float*)d_out;
    char* ws = (char*)d_ws;
    float*  f    = (float*)(ws);                 // 8*8192*64 f32   = 16,777,216 B
    float4* pts4 = (float4*)(ws + 16777216);     // 8*8192 float4   =  1,048,576 B
    int*    fpsI = (int*)   (ws + 17825792);     // 8*1024 i32 (poison 0xAA = not-ready)
    int*    done = (int*)   (ws + 17858560);     // poison-base counter

    float* out0 = out;              // new_xyz      (8,1024,3)
    float* out1 = out + 24576;      // feature_0    (8,128,1024)
    float* out2 = out + 1073152;    // new_xyz copy
    float* out3 = out + 1097728;    // feature_0 copy

    mega_kernel<<<256, 512, 0, stream>>>(x, c1w, c2w,
        bn1g, bn1b, bn1m, bn1v, bn2g, bn2b, bn2m, bn2v,
        l1w, l2w, lb1g, lb1b, lb1m, lb1v, lb2g, lb2b, lb2m, lb2v,
        f, pts4, fpsI, done, out0, out1, out2, out3);
}

// Round 12
// 1042.554 us; speedup vs baseline: 1.0276x; 1.0276x over previous
//
#include <hip/hip_runtime.h>
#include <hip/hip_bf16.h>
#include <math.h>
#include <stdint.h>

#define EPS_BN 1e-5f

constexpr int Nx = 8192;
constexpr int NP = 1024;
constexpr int NWORK = 248;   // worker blocks (grid 256 = 8 fps + 248 workers)
constexpr int NEMB  = 128;   // worker blocks 8..135 also embed a 512-pt slice
#define POISON_I ((int)0xAAAAAAAA)

typedef __attribute__((ext_vector_type(8))) __bf16 bf16x8;
typedef __attribute__((ext_vector_type(4))) float  f32x4;
typedef __attribute__((ext_vector_type(2))) float  f32x2;
typedef unsigned int uint32;
typedef unsigned long long u64;

// ---- DPP wave64 reduction helpers ----
template<int CTRL, int RMASK>
__device__ __forceinline__ u64 dpp_max_u64(u64 k) {
    uint32 klo = (uint32)k, khi = (uint32)(k >> 32);
    uint32 plo = (uint32)__builtin_amdgcn_update_dpp((int)klo, (int)klo, CTRL, RMASK, 0xf, false);
    uint32 phi = (uint32)__builtin_amdgcn_update_dpp((int)khi, (int)khi, CTRL, RMASK, 0xf, false);
    u64 p = ((u64)phi << 32) | plo;
    return (p > k) ? p : k;
}
template<int CTRL, int RMASK>
__device__ __forceinline__ float dpp_max_f32(float v) {
    int t = __builtin_amdgcn_update_dpp(__float_as_int(v), __float_as_int(v), CTRL, RMASK, 0xf, false);
    return fmaxf(v, __int_as_float(t));
}
__device__ __forceinline__ float wave_max_f32(float v) {
    v = dpp_max_f32<0x111, 0xf>(v);   // row_shr:1
    v = dpp_max_f32<0x112, 0xf>(v);   // row_shr:2
    v = dpp_max_f32<0x114, 0xf>(v);   // row_shr:4
    v = dpp_max_f32<0x118, 0xf>(v);   // row_shr:8
    v = dpp_max_f32<0x142, 0xa>(v);   // row_bcast:15 -> rows 1,3
    v = dpp_max_f32<0x143, 0xc>(v);   // row_bcast:31 -> rows 2,3
    return __int_as_float(__builtin_amdgcn_readlane(__float_as_int(v), 63));
}
template<int CTRL, int RMASK>
__device__ __forceinline__ int dpp_sum_i32(int c) {
    int t = __builtin_amdgcn_update_dpp(0, c, CTRL, RMASK, 0xf, true);  // OOB -> 0
    return c + t;
}
__device__ __forceinline__ int wave_sum_i32(int c) {
    c = dpp_sum_i32<0x111, 0xf>(c);
    c = dpp_sum_i32<0x112, 0xf>(c);
    c = dpp_sum_i32<0x114, 0xf>(c);
    c = dpp_sum_i32<0x118, 0xf>(c);
    c = dpp_sum_i32<0x142, 0xa>(c);
    c = dpp_sum_i32<0x143, 0xc>(c);
    return __builtin_amdgcn_readlane(c, 63);
}
template<int CTRL, int RMASK>
__device__ __forceinline__ int dpp_min_i32(int v) {
    int t = __builtin_amdgcn_update_dpp(v, v, CTRL, RMASK, 0xf, false);
    return min(v, t);
}
__device__ __forceinline__ int wave_min_i32(int v) {
    v = dpp_min_i32<0x111, 0xf>(v);
    v = dpp_min_i32<0x112, 0xf>(v);
    v = dpp_min_i32<0x114, 0xf>(v);
    v = dpp_min_i32<0x118, 0xf>(v);
    v = dpp_min_i32<0x142, 0xa>(v);
    v = dpp_min_i32<0x143, 0xc>(v);
    return __builtin_amdgcn_readlane(v, 63);
}

// =================== THE single kernel: fps | embed+worker roles ===================
__global__ __launch_bounds__(512, 1) void mega_kernel(
    const float* __restrict__ x,
    const float* __restrict__ w1, const float* __restrict__ w2,
    const float* g1, const float* b1, const float* m1, const float* v1,
    const float* g2, const float* b2, const float* m2, const float* v2,
    const float* __restrict__ lw1, const float* __restrict__ lw2,
    const float* lg1, const float* lb1, const float* lm1, const float* lv1,
    const float* lg2, const float* lb2, const float* lm2, const float* lv2,
    float* __restrict__ f, float4* __restrict__ pts4, int* fpsI, int* done,
    float* __restrict__ out0, float* __restrict__ out1,
    float* __restrict__ out2, float* __restrict__ out3)
{
    __shared__ __attribute__((aligned(16))) char smemRaw[131200];
    int tid = threadIdx.x;

    if (blockIdx.x < 8) {
        // ================= FPS role (round-8 proven body — best measured) ==========
#pragma clang fp contract(off)
        float4* xyzL = (float4*)smemRaw;                 // 128 KB
        u64*    redK = (u64*)(smemRaw + 131072);         // [2][8]
        int b = blockIdx.x;
        int wid = tid >> 6, lane = tid & 63;
        const float* xb = x + (size_t)b * Nx * 3;
        f32x2 px[8], py[8], pz[8], dist[8];    // 16 pts/thread: pair i = pts (16t+2i, 16t+2i+1)
        {
            const float4* xv = (const float4*)(xb + tid * 48);
            float F[48];
#pragma unroll
            for (int q = 0; q < 12; q++) {
                float4 v = xv[q];
                F[q*4+0]=v.x; F[q*4+1]=v.y; F[q*4+2]=v.z; F[q*4+3]=v.w;
            }
#pragma unroll
            for (int i = 0; i < 8; i++) {
                px[i] = (f32x2){F[(2*i)*3+0], F[(2*i+1)*3+0]};
                py[i] = (f32x2){F[(2*i)*3+1], F[(2*i+1)*3+1]};
                pz[i] = (f32x2){F[(2*i)*3+2], F[(2*i+1)*3+2]};
                dist[i] = (f32x2){1e10f, 1e10f};
            }
#pragma unroll
            for (int j = 0; j < 16; j++) {
                int jj = (j + (tid & 15)) & 15;
                xyzL[tid*16 + jj] = make_float4(F[jj*3], F[jj*3+1], F[jj*3+2], 0.f);
            }
        }
        __syncthreads();
        int far = 0;
        for (int st = 0; st < NP; st++) {
            float4 c = xyzL[far];
            if (tid == 0) {
                __hip_atomic_store(&fpsI[b*NP + st], far, __ATOMIC_RELAXED, __HIP_MEMORY_SCOPE_AGENT);
                int o = (b*NP + st) * 3;
                out0[o]=c.x; out0[o+1]=c.y; out0[o+2]=c.z;
                out2[o]=c.x; out2[o+1]=c.y; out2[o+2]=c.z;
            }
            f32x2 cx = {c.x, c.x}, cy = {c.y, c.y}, cz = {c.z, c.z};
            f32x2 bv2 = {-1.0f, -1.0f};
#pragma unroll
            for (int i = 0; i < 8; i++) {
                f32x2 dx = px[i] - cx, dy = py[i] - cy, dz = pz[i] - cz;
                f32x2 sq = (dx*dx + dy*dy) + dz*dz;    // per-lane IEEE, exact np order
                f32x2 dm = __builtin_elementwise_min(dist[i], sq);
                dist[i] = dm;
                bv2 = __builtin_elementwise_max(bv2, dm);
            }
            float bv = fmaxf(bv2.x, bv2.y);
            // per-lane argmax vs OWN bv (independent of the DPP chain -> overlaps it)
            int bi = tid*16;
#pragma unroll
            for (int i = 7; i >= 0; i--) {          // high->low so lowest idx wins
                if (dist[i].y == bv) bi = tid*16 + 2*i + 1;
                if (dist[i].x == bv) bi = tid*16 + 2*i;
            }
            // wave winner: f32 value reduce, then ballot picks lowest matching lane
            float wv = wave_max_f32(bv);
            u64 mask = __ballot(bv == wv);
            int first = (int)__builtin_ctzll(mask);   // lane order == point-index order
            int wbi = __builtin_amdgcn_readlane(bi, first);
            if (lane == 0)
                redK[(st & 1)*8 + wid] = ((u64)__float_as_uint(wv) << 32) | (uint32)(~wbi);
            __syncthreads();
            // lane-parallel cross-wave combine: 1 ds_read_b64 + 3-level u64 DPP
            u64 k8 = redK[(st & 1)*8 + (lane & 7)];
            k8 = dpp_max_u64<0x111, 0xf>(k8);
            k8 = dpp_max_u64<0x112, 0xf>(k8);
            k8 = dpp_max_u64<0x114, 0xf>(k8);   // lane 7 = max over lanes 0..7
            far = (int)(~(uint32)__builtin_amdgcn_readlane((int)(uint32)k8, 7));
        }
        return;
    }

    // ================= Worker role ====================================================
    int wb = (int)blockIdx.x - 8;

    if (wb < NEMB) {
        // ---- embed a 512-point slice: f + pts4 (LDS overlay, released by sync below) --
        float*  W1L = (float*)smemRaw;                    // 192 f  @0
        float4* W2L = (float4*)(smemRaw + 1024);          // 1024 float4
        float*  s1L = (float*)(smemRaw + 17408);
        float*  m1L = (float*)(smemRaw + 17664);
        float*  b1L = (float*)(smemRaw + 17920);
        float*  s2L = (float*)(smemRaw + 18176);
        float*  m2L = (float*)(smemRaw + 18432);
        float*  b2L = (float*)(smemRaw + 18688);
        if (tid < 192) W1L[tid] = w1[tid];
        for (int i = tid; i < 1024; i += 512) W2L[i] = ((const float4*)w2)[i];
        if (tid < 64) {
            s1L[tid] = g1[tid] * (1.0f / sqrtf(v1[tid] + EPS_BN));
            m1L[tid] = m1[tid];  b1L[tid] = b1[tid];
            s2L[tid] = g2[tid] * (1.0f / sqrtf(v2[tid] + EPS_BN));
            m2L[tid] = m2[tid];  b2L[tid] = b2[tid];
        }
        __syncthreads();
        int n = wb * 512 + tid;                 // 0..65535
        const float* xp = x + (size_t)n * 3;
        float x0 = xp[0], x1 = xp[1], x2 = xp[2];
        {
#pragma clang fp contract(off)
            float nv = (x0 * x0 + x1 * x1) + x2 * x2;   // exact np sum order
            pts4[n] = make_float4(x0, x1, x2, nv);
        }
        float t[64];
#pragma unroll
        for (int e = 0; e < 64; e++) {
            float v = fmaf(x2, W1L[e*3+2], fmaf(x1, W1L[e*3+1], x0 * W1L[e*3]));
            v = (v - m1L[e]) * s1L[e] + b1L[e];
            t[e] = fmaxf(v, 0.0f);
        }
        float acc[64];
#pragma unroll
        for (int o = 0; o < 64; o++) acc[o] = 0.0f;
#pragma unroll
        for (int e4 = 0; e4 < 16; e4++) {
            float a0 = t[e4*4], a1 = t[e4*4+1], a2 = t[e4*4+2], a3 = t[e4*4+3];
#pragma unroll
            for (int o = 0; o < 64; o++) {
                float4 w = W2L[o*16 + e4];
                acc[o] = fmaf(a3, w.w, fmaf(a2, w.z, fmaf(a1, w.y, fmaf(a0, w.x, acc[o]))));
            }
        }
        float4* fo = (float4*)(f + (size_t)n * 64);
#pragma unroll
        for (int q = 0; q < 16; q++) {
            float r0 = fmaxf((acc[q*4+0] - m2L[q*4+0]) * s2L[q*4+0] + b2L[q*4+0], 0.f);
            float r1 = fmaxf((acc[q*4+1] - m2L[q*4+1]) * s2L[q*4+1] + b2L[q*4+1], 0.f);
            float r2 = fmaxf((acc[q*4+2] - m2L[q*4+2]) * s2L[q*4+2] + b2L[q*4+2], 0.f);
            float r3 = fmaxf((acc[q*4+3] - m2L[q*4+3]) * s2L[q*4+3] + b2L[q*4+3], 0.f);
            fo[q] = make_float4(r0, r1, r2, r3);
        }
        __syncthreads();      // LDS free for query phase
        if (tid == 0)
            __hip_atomic_fetch_add(done, 1, __ATOMIC_RELEASE, __HIP_MEMORY_SCOPE_AGENT);
    }

    // ---- query-phase LDS overlay ----
    __bf16* featL = (__bf16*)smemRaw;                 // 8704 B
    __bf16* h1L   = (__bf16*)(smemRaw + 8704);        // 8704 B
    float*  cf    = (float*) (smemRaw + 17408);       // 256 B
    int*    rowL  = (int*)   (smemRaw + 17664);       // 128 B
    int*    redC  = (int*)   (smemRaw + 17792);       // [2][8]
    int*    redM  = (int*)   (smemRaw + 17856);       // [2][8]
    int*    misc  = (int*)   (smemRaw + 17920);       // [0]=cnt [1]=idx

    int wv = tid >> 6, lane = tid & 63;
    int l15 = lane & 15, quad = lane >> 4;
    int nbase = wv * 16;
    const f32x4 vzero = {0.f, 0.f, 0.f, 0.f};

    // per-wave weight fragments / bn params, straight from f32 inputs (no prep kernel)
    bf16x8 bf1[4], bf2[4];
#pragma unroll
    for (int kt = 0; kt < 4; kt++) {
        const float* p1 = lw1 + (size_t)(nbase + l15) * 128 + kt*32 + quad*8;
        const float* p2 = lw2 + (size_t)(nbase + l15) * 128 + kt*32 + quad*8;
        bf16x8 a1, a2;
#pragma unroll
        for (int j = 0; j < 8; j++) { a1[j] = (__bf16)p1[j]; a2[j] = (__bf16)p2[j]; }
        bf1[kt] = a1; bf2[kt] = a2;
    }
    int oc = nbase + l15;
    float sc1 = lg1[oc] * (1.0f / sqrtf(lv1[oc] + EPS_BN));
    float mm1 = lm1[oc], bb1 = lb1[oc];
    float sc2 = lg2[oc] * (1.0f / sqrtf(lv2[oc] + EPS_BN));
    float mm2 = lm2[oc], bb2 = lb2[oc];

    // wait for embed completion (cross-XCD: acquire fence before reading f/pts4)
    if (tid == 0) {
        while (__hip_atomic_load(done, __ATOMIC_RELAXED, __HIP_MEMORY_SCOPE_AGENT) != POISON_I + NEMB)
            __builtin_amdgcn_s_sleep(8);
    }
    __syncthreads();
    __threadfence();

    for (int t = wb; t < 8192; t += NWORK) {
        int b = t & 7, s = t >> 3;          // s-major: workers trail fps monotonically
        int q = (b << 10) | s;
        if (tid == 0) {
            int v;
            while ((v = __hip_atomic_load(&fpsI[q], __ATOMIC_RELAXED, __HIP_MEMORY_SCOPE_AGENT)) < 0)
                __builtin_amdgcn_s_sleep(2);
            misc[1] = v;
            misc[0] = 0;
        }
        __syncthreads();
        int cIdx = misc[1];
        if (tid < 16) {      // center features -> cf (consumed after many barriers)
            float4 v = *(const float4*)(f + ((size_t)b * Nx + cIdx) * 64 + tid * 4);
            cf[tid*4]=v.x; cf[tid*4+1]=v.y; cf[tid*4+2]=v.z; cf[tid*4+3]=v.w;
        }
        // ---- KNN radix-select (512 thr, 16 keys each) ----
        uint32 key[16];
        {
#pragma clang fp contract(off)
            const float4* P = pts4 + (size_t)b * Nx;
            float4 qp = P[cIdx];
#pragma unroll
            for (int i = 0; i < 16; i++) {
                int n = tid + (i << 9);
                float4 p = P[n];
                float dot = (qp.x * p.x + qp.y * p.y) + qp.z * p.z;   // exact ref order
                float d = (qp.w + p.w) - 2.0f * dot;
                uint32 u = __float_as_uint(d);
                key[i] = (u & 0x80000000u) ? ~u : (u | 0x80000000u);
            }
        }
        uint32 prefix = 0; int krem = 32;
        for (int bit = 31; bit >= 0; bit--) {
            uint32 sv = prefix >> bit;
            int cnt = 0;
#pragma unroll
            for (int i = 0; i < 16; i++)
                cnt += ((key[i] >> bit) == sv) ? 1 : 0;
            cnt = wave_sum_i32(cnt);
            if (lane == 0) redC[(bit & 1)*8 + wv] = cnt;
            __syncthreads();
            int total = 0;
#pragma unroll
            for (int j = 0; j < 8; j++) total += redC[(bit & 1)*8 + j];
            if (total < krem) { prefix |= (1u << bit); krem -= total; }
        }
#pragma unroll
        for (int i = 0; i < 16; i++) {
            if (key[i] < prefix) {
                int pos = atomicAdd(&misc[0], 1);
                rowL[pos] = tid + (i << 9);
            }
        }
        __syncthreads();
        int last = -1;
        for (int tt = 0; tt < krem; tt++) {    // krem is block-uniform
            int local = 0x7fffffff;
#pragma unroll
            for (int i = 0; i < 16; i++) {
                int n = tid + (i << 9);
                if (key[i] == prefix && n > last && n < local) local = n;
            }
            local = wave_min_i32(local);
            if (lane == 0) redM[(tt & 1)*8 + wv] = local;
            __syncthreads();
            int g = 0x7fffffff;
#pragma unroll
            for (int j = 0; j < 8; j++) g = min(g, redM[(tt & 1)*8 + j]);
            if (tid == 0) rowL[32 - krem + tt] = g;
            last = g;
        }
        __syncthreads();                        // rowL final
        // ---- build feat = [f_nb - f_c | f_c] in bf16 ----
        {
            int k = tid >> 4, j0 = (tid & 15) * 4;
            int nbr = rowL[k];
            float4 v = *(const float4*)(f + ((size_t)b * Nx + nbr) * 64 + j0);
            float c0 = cf[j0], c1 = cf[j0+1], c2 = cf[j0+2], c3 = cf[j0+3];
            __bf16* dl = featL + k * 136 + j0;
            dl[0]=(__bf16)(v.x-c0); dl[1]=(__bf16)(v.y-c1); dl[2]=(__bf16)(v.z-c2); dl[3]=(__bf16)(v.w-c3);
            __bf16* dr = dl + 64;
            dr[0]=(__bf16)c0; dr[1]=(__bf16)c1; dr[2]=(__bf16)c2; dr[3]=(__bf16)c3;
        }
        __syncthreads();
        // ---- layer 1: (32x128)@(128x16 per wave) ----
        f32x4 acc[2];
        acc[0] = vzero; acc[1] = vzero;
#pragma unroll
        for (int mt = 0; mt < 2; mt++)
#pragma unroll
            for (int kt = 0; kt < 4; kt++) {
                bf16x8 a = *(const bf16x8*)(featL + (mt*16 + l15) * 136 + kt*32 + quad*8);
                acc[mt] = __builtin_amdgcn_mfma_f32_16x16x32_bf16(a, bf1[kt], acc[mt], 0, 0, 0);
            }
#pragma unroll
        for (int mt = 0; mt < 2; mt++)
#pragma unroll
            for (int rj = 0; rj < 4; rj++) {
                float h = fmaxf((acc[mt][rj] - mm1) * sc1 + bb1, 0.0f);
                h1L[(mt*16 + quad*4 + rj) * 136 + oc] = (__bf16)h;
            }
        __syncthreads();
        // ---- layer 2 + k-max ----
        acc[0] = vzero; acc[1] = vzero;
#pragma unroll
        for (int mt = 0; mt < 2; mt++)
#pragma unroll
            for (int kt = 0; kt < 4; kt++) {
                bf16x8 a = *(const bf16x8*)(h1L + (mt*16 + l15) * 136 + kt*32 + quad*8);
                acc[mt] = __builtin_amdgcn_mfma_f32_16x16x32_bf16(a, bf2[kt], acc[mt], 0, 0, 0);
            }
        float vmx = 0.0f;                       // relu => >= 0
#pragma unroll
        for (int mt = 0; mt < 2; mt++)
#pragma unroll
            for (int rj = 0; rj < 4; rj++) {
                float h = fmaxf((acc[mt][rj] - mm2) * sc2 + bb2, 0.0f);
                vmx = fmaxf(vmx, h);
            }
        vmx = fmaxf(vmx, __shfl_xor(vmx, 16));
        vmx = fmaxf(vmx, __shfl_xor(vmx, 32));
        if (quad == 0) {
            size_t off = (size_t)b * (128*1024) + (size_t)oc * 1024 + s;
            out1[off] = vmx;
            out3[off] = vmx;
        }
        __syncthreads();                        // LDS reuse next query
    }
}

extern "C" void kernel_launch(void* const* d_in, const int* in_sizes, int n_in,
                              void* d_out, int out_size, void* d_ws, size_t ws_size,
                              hipStream_t stream)
{
    const float* x    = (const float*)d_in[0];
    const float* c1w  = (const float*)d_in[1];
    const float* c2w  = (const float*)d_in[2];
    const float* l1w  = (const float*)d_in[3];
    const float* l2w  = (const float*)d_in[4];
    const float* bn1g = (const float*)d_in[5];
    const float* bn1b = (const float*)d_in[6];
    const float* bn1m = (const float*)d_in[7];
    const float* bn1v = (const float*)d_in[8];
    const float* bn2g = (const float*)d_in[9];
    const float* bn2b = (const float*)d_in[10];
    const float* bn2m = (const float*)d_in[11];
    const float* bn2v = (const float*)d_in[12];
    const float* lb1g = (const float*)d_in[13];
    const float* lb1b = (const float*)d_in[14];
    const float* lb1m = (const float*)d_in[15];
    const float* lb1v = (const float*)d_in[16];
    const float* lb2g = (const float*)d_in[17];
    const float* lb2b = (const float*)d_in[18];
    const float* lb2m = (const float*)d_in[19];
    const float* lb2v = (const float*)d_in[20];

    float* out = (float*)d_out;
    char* ws = (char*)d_ws;
    float*  f    = (float*)(ws);                 // 8*8192*64 f32   = 16,777,216 B
    float4* pts4 = (float4*)(ws + 16777216);     // 8*8192 float4   =  1,048,576 B
    int*    fpsI = (int*)   (ws + 17825792);     // 8*1024 i32 (poison 0xAA = not-ready)
    int*    done = (int*)   (ws + 17858560);     // poison-base counter

    float* out0 = out;              // new_xyz      (8,1024,3)
    float* out1 = out + 24576;      // feature_0    (8,128,1024)
    float* out2 = out + 1073152;    // new_xyz copy
    float* out3 = out + 1097728;    // feature_0 copy

    mega_kernel<<<256, 512, 0, stream>>>(x, c1w, c2w,
        bn1g, bn1b, bn1m, bn1v, bn2g, bn2b, bn2m, bn2v,
        l1w, l2w, lb1g, lb1b, lb1m, lb1v, lb2g, lb2b, lb2m, lb2v,
        f, pts4, fpsI, done, out0, out1, out2, out3);
}